// Round 9
// baseline (285.357 us; speedup 1.0000x reference)
//
#include <hip/hip_runtime.h>
#include <hip/hip_bf16.h>

typedef __attribute__((ext_vector_type(8))) short short8;
typedef __attribute__((ext_vector_type(16))) float f32x16;
typedef __attribute__((ext_vector_type(4))) float f32x4;

#define LL 16
#define NP3 23
#define NE 10
#define NC 128
#define KI 24            // fused K stride per i: 23 U3 slots + 1 U2/zero slot
#define NSKH 12          // K-steps per block (K split in halves of 192)
#define RB 512           // rows per block
#define THREADS 512
#define BHALF 98304      // bytes of one K-half of B: 96 frags * 64 lanes * 16 B
#define XSTR 520         // xsT row stride in f32 (520 mod 32 = 8 -> 4-way worst)
#define WSTR 29          // wys row stride in bf16 (29 odd -> conflict-free rows)

static __device__ __forceinline__ short f2bs(float f) {
    __hip_bfloat16 h = __float2bfloat16(f);
    short s;
    __builtin_memcpy(&s, &h, 2);
    return s;
}

// ---- kernel 1: pack U3/U2 -> fragment-major bf16 B, K-half-major (verified R8) ----
__global__ void build_B(const float* __restrict__ U3, const float* __restrict__ U2,
                        __hip_bfloat16* __restrict__ Bf) {
    int g   = blockIdx.x;            // 0..191
    int kh  = g / 96, r96 = g % 96;
    int t   = r96 / NSKH, s12 = r96 % NSKH;
    int s   = kh * NSKH + s12;
    int lane = threadIdx.x;
    int col  = t * 32 + (lane & 31);
    int hi   = lane >> 5;
    short8 v;
#pragma unroll
    for (int j = 0; j < 8; ++j) {
        int K = s * 16 + hi * 8 + j;
        int i = K / KI, kk = K - i * KI;
        float f;
        if (kk < NP3)    f = U3[((size_t)col * LL + i) * NP3 + kk];
        else if (i < 4)  f = U2[col * 4 + i];
        else             f = 0.f;
        v[j] = f2bs(f);
    }
    *reinterpret_cast<short8*>(Bf + ((size_t)g * 64 + lane) * 8) = v;
}

// A-build for compile-time K-base: all indices constant-fold (verified R8)
#define BUILD_A(DST, KB)                                                      \
    _Pragma("unroll")                                                         \
    for (int s = 0; s < NSKH; ++s) {                                          \
        short8 av;                                                            \
        _Pragma("unroll")                                                     \
        for (int j = 0; j < 8; ++j) {                                         \
            const int K  = (KB) + s * 16 + j;                                 \
            const int i  = K / KI;                                            \
            const int kk = K - i * KI;                                        \
            float f = (kk < NP3) ? xr[i] * wr[kk]                             \
                                 : ((i < 4) ? w2r[i] : 0.f);                  \
            av[j] = f2bs(f);                                                  \
        }                                                                     \
        DST[s] = av;                                                          \
    }

// DPP-based partial-sum (VALU pipe, not LDS): v += dpp_perm(v)
#define DPP_ADD(v, CTRL)                                                      \
    {                                                                         \
        int _s = __builtin_bit_cast(int, (v));                                \
        int _p = __builtin_amdgcn_update_dpp(0, _s, (CTRL), 0xF, 0xF, true);  \
        (v) += __builtin_bit_cast(float, _p);                                 \
    }

// ---- kernel 2: B-half LDS-resident; wave = 2 rowtiles x full N; A built once ----
__global__ __launch_bounds__(THREADS, 2)
void contract_k(const float* __restrict__ x, const float* __restrict__ y,
                const float* __restrict__ W3, const float* __restrict__ W2,
                const float* __restrict__ W1, const float* __restrict__ U1,
                const __hip_bfloat16* __restrict__ Bf, float* __restrict__ out) {
    __shared__ __align__(16) char Bs[BHALF];          // 96 KB
    __shared__ float xsT[LL][XSTR];                   // 33280 B, transposed x
    __shared__ __hip_bfloat16 wys[RB][WSTR];          // 29696 B: 0..22 Wy3, 23..26 Wy2, 27 Wy1, 28 du

    const int tid    = threadIdx.x;
    const int rowblk = blockIdx.x >> 1;
    const int kh     = blockIdx.x & 1;
    const int m0     = rowblk * RB;

    // one-time B-half load into regs (lands under the whole prologue)
    f32x4 st[12];
    {
        const f32x4* p = reinterpret_cast<const f32x4*>(Bf) + (size_t)kh * (BHALF / 16) + tid;
#pragma unroll
        for (int j = 0; j < 12; ++j) st[j] = p[j * THREADS];
    }

    // stage x transposed: xsT[i][r] = x[m0+r][i]
#pragma unroll
    for (int k2 = 0; k2 < (RB * LL) / THREADS; ++k2) {
        int v = tid + k2 * THREADS;
        xsT[v & 15][v >> 4] = x[(size_t)m0 * LL + v];
    }
    __syncthreads();

    // Wy phase: each thread owns row r = tid, loops idx 0..28 (y loaded once)
    {
        const int r = tid;
        const int b = rowblk * 4 + (r >> 7);
        const int c = r & (NC - 1);
        float yv[NE];
#pragma unroll
        for (int e = 0; e < NE; ++e) yv[e] = y[(size_t)b * NE + e];
#pragma unroll
        for (int idx = 0; idx < 29; ++idx) {
            float s = 0.f;
            if (idx < NP3) {
#pragma unroll
                for (int e = 0; e < NE; ++e) s += yv[e] * W3[(e * NP3 + idx) * NC + c];
            } else if (idx < 27) {
#pragma unroll
                for (int e = 0; e < NE; ++e) s += yv[e] * W2[(e * 4 + (idx - NP3)) * NC + c];
            } else if (idx == 27) {
#pragma unroll
                for (int e = 0; e < NE; ++e) s += yv[e] * W1[e * NC + c];
            } else {
                for (int w = 0; w < LL; ++w) s += U1[w] * xsT[w][r];
            }
            wys[r][idx] = __float2bfloat16(s);
        }
    }

    // commit B-half to LDS
    {
        f32x4* q = reinterpret_cast<f32x4*>(Bs) + tid;
#pragma unroll
        for (int j = 0; j < 12; ++j) q[j * THREADS] = st[j];
    }
    __syncthreads();     // Bs + wys visible; LDS is read-only from here on

    // wave geometry: wave wv owns rowtiles {2wv, 2wv+1}, full N range
    const int lane = tid & 63;
    const int wv   = tid >> 6;
    const int l31  = lane & 31;
    const int hi   = lane >> 5;
    const int bsel = l31 >> 4;

    // build A fragments once: A2[rr][s] = Z[arow][kh*192 + s*16 + hi*8 + j]
    short8 A2[2][NSKH];
#pragma unroll
    for (int rr = 0; rr < 2; ++rr) {
        const int arow = (wv * 2 + rr) * 32 + l31;
        float xr[LL], wr[NP3], w2r[4];
#pragma unroll
        for (int i = 0; i < LL; ++i) xr[i] = xsT[i][arow];
#pragma unroll
        for (int k = 0; k < NP3; ++k) wr[k] = __bfloat162float(wys[arow][k]);
#pragma unroll
        for (int i = 0; i < 4; ++i) w2r[i] = __bfloat162float(wys[arow][NP3 + i]);
        if (kh == 0) {
            if (hi == 0) { BUILD_A(A2[rr], 0) }   else { BUILD_A(A2[rr], 8) }
        } else {
            if (hi == 0) { BUILD_A(A2[rr], 192) } else { BUILD_A(A2[rr], 200) }
        }
    }

    float acc0[16], acc1[16];
#pragma unroll
    for (int q2 = 0; q2 < 16; ++q2) { acc0[q2] = 0.f; acc1[q2] = 0.f; }

    // main loop: 8 N-tiles x 12 K-steps; each b-frag feeds both rowtiles
    const short8* BsV = reinterpret_cast<const short8*>(Bs);
#pragma unroll
    for (int t = 0; t < 8; ++t) {
        f32x16 a0, a1;
#pragma unroll
        for (int q2 = 0; q2 < 16; ++q2) { a0[q2] = 0.f; a1[q2] = 0.f; }
        __builtin_amdgcn_s_setprio(1);
#pragma unroll
        for (int s = 0; s < NSKH; ++s) {
            short8 bfrag = BsV[(t * NSKH + s) * 64 + lane];
            a0 = __builtin_amdgcn_mfma_f32_32x32x16_bf16(A2[0][s], bfrag, a0, 0, 0, 0);
            a1 = __builtin_amdgcn_mfma_f32_32x32x16_bf16(A2[1][s], bfrag, a1, 0, 0, 0);
        }
        __builtin_amdgcn_s_setprio(0);
        // fold: acc += a * x[row][w=2t+bsel]; xw via broadcast b128 from xsT
        const int c = 2 * t + bsel;
#pragma unroll
        for (int g = 0; g < 4; ++g) {
            f32x4 xw0 = *reinterpret_cast<const f32x4*>(&xsT[c][(wv * 2 + 0) * 32 + 4 * hi + 8 * g]);
            f32x4 xw1 = *reinterpret_cast<const f32x4*>(&xsT[c][(wv * 2 + 1) * 32 + 4 * hi + 8 * g]);
#pragma unroll
            for (int j = 0; j < 4; ++j) {
                acc0[g * 4 + j] += a0[g * 4 + j] * xw0[j];
                acc1[g * 4 + j] += a1[g * 4 + j] * xw1[j];
            }
        }
    }

    // epilogue: *x_x (per-lane col), reduce 32 lanes via DPP + one ds_swizzle, atomicAdd
#pragma unroll
    for (int rr = 0; rr < 2; ++rr) {
#pragma unroll
        for (int q2 = 0; q2 < 16; ++q2) {
            const int row = (wv * 2 + rr) * 32 + (q2 & 3) + 8 * (q2 >> 2) + 4 * hi;
            float v = (rr ? acc1[q2] : acc0[q2]) * xsT[lane & 15][row];
            DPP_ADD(v, 0xB1);    // quad_perm xor1
            DPP_ADD(v, 0x4E);    // quad_perm xor2
            DPP_ADD(v, 0x141);   // row_half_mirror (8-sum)
            DPP_ADD(v, 0x140);   // row_mirror (16-sum)
            {
                int _p = __builtin_amdgcn_ds_swizzle(__builtin_bit_cast(int, v), 0x401F);
                v += __builtin_bit_cast(float, _p);   // xor16 -> 32-lane sum
            }
            if (l31 == 0) {
                float add = v;
                if (kh == 0)
                    add += __bfloat162float(wys[row][27]) * __bfloat162float(wys[row][28]);
                atomicAdd(out + m0 + row, add);
            }
        }
    }
}

extern "C" void kernel_launch(void* const* d_in, const int* in_sizes, int n_in,
                              void* d_out, int out_size, void* d_ws, size_t ws_size,
                              hipStream_t stream) {
    const float* x  = (const float*)d_in[0];
    const float* y  = (const float*)d_in[1];
    const float* U3 = (const float*)d_in[2];
    const float* U2 = (const float*)d_in[3];
    const float* U1 = (const float*)d_in[4];
    const float* W3 = (const float*)d_in[5];
    const float* W2 = (const float*)d_in[6];
    const float* W1 = (const float*)d_in[7];
    __hip_bfloat16* Bf = (__hip_bfloat16*)d_ws;   // 192 frags * 64 lanes * 8 bf16 * 2B

    hipMemsetAsync(d_out, 0, (size_t)out_size * sizeof(float), stream);
    build_B<<<192, 64, 0, stream>>>(U3, U2, Bf);
    contract_k<<<1024, THREADS, 0, stream>>>(x, y, W3, W2, W1, U1, Bf, (float*)d_out);
}